// Round 1
// 5186.841 us; speedup vs baseline: 1.1361x; 1.1361x over previous
//
#include <hip/hip_runtime.h>
#include <hip/hip_bf16.h>
#include <math.h>

#define T_STEPS 16
#define N_NODES 20
#define BATCH 4096
#define F_DIM 64
#define BN 81920
#define E_EDGES 327680
#define D1 1280
#define D2 640
#define D3 320

typedef __attribute__((ext_vector_type(8))) short short8;
typedef __attribute__((ext_vector_type(4))) float floatx4;

static __device__ __forceinline__ float bf2f(__hip_bfloat16 v) { return __bfloat162float(v); }
static __device__ __forceinline__ float sigmoidf_(float x) { return 1.f / (1.f + expf(-x)); }
static __device__ __forceinline__ float loadf(const void* p, size_t i, int isf32) {
    return isf32 ? ((const float*)p)[i] : bf2f(((const __hip_bfloat16*)p)[i]);
}
static __device__ __forceinline__ float bflo(unsigned int u) { return __uint_as_float(u << 16); }
static __device__ __forceinline__ float bfhi(unsigned int u) { return __uint_as_float(u & 0xffff0000u); }
static __device__ __forceinline__ unsigned int f2bf_bits(float f) {
    __hip_bfloat16 b = __float2bfloat16(f);
    unsigned short us;
    __builtin_memcpy(&us, &b, 2);
    return (unsigned int)us;
}

// A6 element-column layout (row stride 384 bf16 = 768 B):
//   [0:Xt | 64:H | 128:X1 | 192:H1 | 256:X2 | 320:H2]
// After gates:  G  -> col 0   (Xt dead)
// After G1-spmm: G1 -> col 128 (X1 dead)
// After G2-spmm: G2 -> col 256 (X2 dead)
// cand epilogue: Hn -> col 64, X_{t+1} -> col 0

// ---------------- dtype detection (bf16 vs f32 inputs) ----------------
__global__ void detect_dtype(const void* __restrict__ x, int* __restrict__ flag) {
    int lane = threadIdx.x;
    const unsigned short* u = (const unsigned short*)x;
    int bad = 0;
    for (int i = lane; i < 256; i += 64) {
        int e = (u[i] >> 7) & 0xFF;
        if (e >= 141) bad = 1;
    }
    unsigned long long m = __ballot(bad != 0);
    if (lane == 0) flag[0] = (m != 0ull) ? 1 : 0;
}

// ---------------- CSR build ----------------
__global__ void deg_count_kernel(const int* __restrict__ ei, const void* __restrict__ ew,
                                 float* __restrict__ deg, int* __restrict__ counts,
                                 const int* __restrict__ flagp) {
    int isf32 = *flagp;
    int e = blockIdx.x * 256 + threadIdx.x;
    if (e < E_EDGES) {
        atomicAdd(&deg[ei[e]], loadf(ew, e, isf32));
        atomicAdd(&counts[ei[E_EDGES + e]], 1);
    }
}

__global__ void scan_kernel(const int* __restrict__ counts, int* __restrict__ rowptr,
                            int* __restrict__ cursor) {
    __shared__ int s[1024];
    int t = threadIdx.x;
    int base = t * 80;
    int sum = 0;
    for (int i = 0; i < 80; ++i) sum += counts[base + i];
    s[t] = sum;
    __syncthreads();
    for (int off = 1; off < 1024; off <<= 1) {
        int v = (t >= off) ? s[t - off] : 0;
        __syncthreads();
        s[t] += v;
        __syncthreads();
    }
    int run = (t > 0) ? s[t - 1] : 0;
    for (int i = 0; i < 80; ++i) {
        rowptr[base + i] = run;
        cursor[base + i] = run;
        run += counts[base + i];
    }
    if (t == 1023) rowptr[BN] = run;
}

__global__ void fill_kernel(const int* __restrict__ ei, const void* __restrict__ ew,
                            const float* __restrict__ deg,
                            int* __restrict__ cursor, int2* __restrict__ cpack,
                            const int* __restrict__ flagp) {
    int isf32 = *flagp;
    int e = blockIdx.x * 256 + threadIdx.x;
    if (e < E_EDGES) {
        int s = ei[e], d = ei[E_EDGES + e];
        float w = loadf(ew, e, isf32);
        float ds = deg[s], dd = deg[d];
        float is = (ds > 0.f) ? (1.f / sqrtf(ds)) : 0.f;
        float id = (dd > 0.f) ? (1.f / sqrtf(dd)) : 0.f;
        int p = atomicAdd(&cursor[d], 1);
        cpack[p] = make_int2(s, __float_as_int(-is * w * id));
    }
}

// ---------------- weight prep ----------------
// WgT[192][384]: n = grp*64+cc (z|r|hx), k-order matches A6 cols:
//   m in {X-T0, H-T0, X-T1, H-T1, X-T2, H-T2}  (m even = X-chain, odd = H-chain)
// Cheb fold onto stored [V, L V, L^2 V]: c0 = W0 - W2, c1 = W1, c2 = 2 W2.
// WcT[64][192] from Whh (k-order [G,G1,G2], same fold); W1T/W2T transposed MLP.
__global__ void prep_weights(const void* Wxz, const void* Whz,
                             const void* Wxr, const void* Whr,
                             const void* Wxh, const void* Whh,
                             const void* bxz, const void* bhz,
                             const void* bxr, const void* bhr,
                             const void* bxh, const void* bhh,
                             const void* W1, const void* b1,
                             const void* W2, const void* b2,
                             const void* W3, const void* b3,
                             __hip_bfloat16* WgT, __hip_bfloat16* WcT,
                             float* biasg, float* biasc,
                             __hip_bfloat16* W1T, float* bias1,
                             __hip_bfloat16* W2T, float* bias2,
                             float* W3f, float* b3f, const int* __restrict__ flagp) {
    int isf32 = *flagp;
    int tid = blockIdx.x * 256 + threadIdx.x;
    if (tid < 73728) {
        int n = tid / 384, kk = tid - (tid / 384) * 384;
        int m = kk >> 6, jj = kk & 63;
        int grp = n >> 6, cc = n & 63;
        const void* Wx = (grp == 0) ? Wxz : ((grp == 1) ? Wxr : Wxh);
        const void* Wh = (grp == 0) ? Whz : ((grp == 1) ? Whr : nullptr);
        int ch = m & 1;          // 0 = X-chain, 1 = H-chain
        int ti = m >> 1;         // Chebyshev index 0..2
        const void* W = ch ? Wh : Wx;
        float v = 0.f;
        int o = jj * 64 + cc;
        if (W) {
            if (ti == 0)      v = loadf(W, o, isf32) - loadf(W, 2 * 4096 + o, isf32);
            else if (ti == 1) v = loadf(W, 4096 + o, isf32);
            else              v = 2.f * loadf(W, 2 * 4096 + o, isf32);
        }
        WgT[tid] = __float2bfloat16(v);
    } else if (tid < 86016) {
        int t2 = tid - 73728;
        int n = t2 / 192, kk = t2 - (t2 / 192) * 192;
        int m = kk >> 6, jj = kk & 63;
        int o = jj * 64 + n;
        float v;
        if (m == 0)      v = loadf(Whh, o, isf32) - loadf(Whh, 2 * 4096 + o, isf32);
        else if (m == 1) v = loadf(Whh, 4096 + o, isf32);
        else             v = 2.f * loadf(Whh, 2 * 4096 + o, isf32);
        WcT[t2] = __float2bfloat16(v);
    } else if (tid < 86208) {
        int c = tid - 86016;
        int grp = c >> 6, cc = c & 63;
        float v = (grp == 0) ? (loadf(bxz, cc, isf32) + loadf(bhz, cc, isf32))
                 : (grp == 1) ? (loadf(bxr, cc, isf32) + loadf(bhr, cc, isf32))
                              : loadf(bxh, cc, isf32);
        biasg[c] = v;
    } else if (tid < 86272) {
        biasc[tid - 86208] = loadf(bhh, tid - 86208, isf32);
    } else if (tid < 86912) {
        bias1[tid - 86272] = loadf(b1, tid - 86272, isf32);
    } else if (tid < 87232) {
        bias2[tid - 86912] = loadf(b2, tid - 86912, isf32);
    } else if (tid < 87872) {
        W3f[tid - 87232] = loadf(W3, tid - 87232, isf32);
    } else if (tid < 87874) {
        b3f[tid - 87872] = loadf(b3, tid - 87872, isf32);
    } else if (tid < 907074) {
        int t = tid - 87874;                       // W1T[n][k] = W1[k][n]
        int n = t / 1280, k = t - (t / 1280) * 1280;
        W1T[t] = __float2bfloat16(loadf(W1, (size_t)k * 640 + n, isf32));
    } else if (tid < 1111874) {
        int t = tid - 907074;                      // W2T[n][k] = W2[k][n]
        int n = t / 640, k = t - (t / 640) * 640;
        W2T[t] = __float2bfloat16(loadf(W2, (size_t)k * 320 + n, isf32));
    }
}

// ---------------- X_0 staging: A6 col 0 <- x[0] ----------------
__global__ void init_x_kernel(const void* __restrict__ x, const int* __restrict__ flagp,
                              __hip_bfloat16* __restrict__ A6) {
    int isf32 = *flagp;
    int idx = blockIdx.x * 256 + threadIdx.x;
    int r = idx >> 6, c = idx & 63;
    A6[(size_t)r * 384 + c] = __float2bfloat16(loadf(x, idx, isf32));
}

// ---------------- paired-chain SpMV: one 256B gather serves both chains ----------------
// Reads byte-cols [in_boff .. in_boff+255] of neighbor rows (two adjacent 64-elem
// chains), writes byte-cols [out_boff .. out_boff+255] of own row.
// Lanes 0-31: first chain (element pairs), lanes 32-63: second chain.
__global__ void phase_pair_kernel(const int* __restrict__ rowptr, const int2* __restrict__ cpack,
                                  __hip_bfloat16* __restrict__ A6, int in_boff, int out_boff) {
    int row = __builtin_amdgcn_readfirstlane(blockIdx.x * 4 + (threadIdx.x >> 6));
    int lane = threadIdx.x & 63;
    int e0 = rowptr[row], e1 = rowptr[row + 1];
    const char* base = (const char*)A6 + in_boff;
    int boff = lane * 4;
    float ax = 0.f, ay = 0.f, bx = 0.f, by = 0.f;
    int e = e0;
    for (; e + 2 <= e1; e += 2) {
        int2 c0 = cpack[e], c1 = cpack[e + 1];
        unsigned int u0 = *(const unsigned int*)(base + (size_t)c0.x * 768 + boff);
        unsigned int u1 = *(const unsigned int*)(base + (size_t)c1.x * 768 + boff);
        float v0 = __int_as_float(c0.y), v1 = __int_as_float(c1.y);
        ax = fmaf(v0, bflo(u0), ax); ay = fmaf(v0, bfhi(u0), ay);
        bx = fmaf(v1, bflo(u1), bx); by = fmaf(v1, bfhi(u1), by);
    }
    if (e < e1) {
        int2 c0 = cpack[e];
        unsigned int u0 = *(const unsigned int*)(base + (size_t)c0.x * 768 + boff);
        float v0 = __int_as_float(c0.y);
        ax = fmaf(v0, bflo(u0), ax); ay = fmaf(v0, bfhi(u0), ay);
    }
    ax += bx; ay += by;
    unsigned int pk = f2bf_bits(ax) | (f2bf_bits(ay) << 16);
    *(unsigned int*)((char*)A6 + (size_t)row * 768 + out_boff +
                     ((lane >> 5) << 7) + ((lane & 31) << 2)) = pk;
}

// single-chain SpMV for the G-chain (element-col in_off -> out_off)
__global__ void spmm_b_kernel(const int* __restrict__ rowptr, const int2* __restrict__ cpack,
                              __hip_bfloat16* __restrict__ A6, int in_off, int out_off) {
    int row = __builtin_amdgcn_readfirstlane(blockIdx.x * 4 + (threadIdx.x >> 6));
    int lane = threadIdx.x & 63;
    int e0 = rowptr[row], e1 = rowptr[row + 1];
    float acc = 0.f, acc2 = 0.f;
    int e = e0;
    for (; e + 2 <= e1; e += 2) {
        int2 c0 = cpack[e], c1 = cpack[e + 1];
        acc  = fmaf(__int_as_float(c0.y), bf2f(A6[(size_t)c0.x * 384 + in_off + lane]), acc);
        acc2 = fmaf(__int_as_float(c1.y), bf2f(A6[(size_t)c1.x * 384 + in_off + lane]), acc2);
    }
    if (e < e1) {
        int2 c0 = cpack[e];
        acc = fmaf(__int_as_float(c0.y), bf2f(A6[(size_t)c0.x * 384 + in_off + lane]), acc);
    }
    A6[(size_t)row * 384 + out_off + lane] = __float2bfloat16(acc + acc2);
}

// ---------------- MFMA GEMM (fragment-direct, no LDS) ----------------
// C[M x N] = epi(A[M x K]_bf16 @ WT[N x K]_bf16^T + bias)
// KBS: element stride between 64-wide k-blocks in A (64 = dense, 128 = G-chain).
// EPI: 0 = relu -> C(bf16); 1 = gates (Z f32, G=sig(R)*Hf -> A6 col0, hx f32);
//      2 = cand+GRU (Hn -> Hf + A6 col64, X_{t+1} -> A6 col0 when xsrc != null)
template <int MW, int NT, int EPI, int KBS>
__launch_bounds__(256)
__global__ void mfma_gemm(const __hip_bfloat16* __restrict__ A, int lda,
                          const __hip_bfloat16* __restrict__ WT, int ldk,
                          const float* __restrict__ bias, int K,
                          float* __restrict__ Zbuf, float* __restrict__ hxbuf,
                          float* __restrict__ Hf, __hip_bfloat16* A6,
                          __hip_bfloat16* __restrict__ C, int ldc,
                          const void* __restrict__ xsrc, unsigned long long xoff,
                          const int* __restrict__ flagp) {
    int wave = threadIdx.x >> 6;
    int lane = threadIdx.x & 63;
    int l15 = lane & 15, quad = lane >> 4;
    int m0 = blockIdx.x * (MW * 64) + wave * (MW * 16);
    int n0 = blockIdx.y * (NT * 16);
    int isf32 = 0;
    if (EPI == 2 && flagp) isf32 = *flagp;

    floatx4 acc[MW][NT];
#pragma unroll
    for (int mi = 0; mi < MW; ++mi)
#pragma unroll
        for (int nt = 0; nt < NT; ++nt) acc[mi][nt] = (floatx4){0.f, 0.f, 0.f, 0.f};

    for (int k0 = 0; k0 < K; k0 += 32) {
        int kb = k0 >> 6, kr = k0 & 63;
        size_t aoff = (size_t)kb * KBS + kr + quad * 8;
        short8 a[MW];
#pragma unroll
        for (int mi = 0; mi < MW; ++mi)
            a[mi] = *(const short8*)(A + (size_t)(m0 + mi * 16 + l15) * lda + aoff);
#pragma unroll
        for (int nt = 0; nt < NT; ++nt) {
            short8 b = *(const short8*)(WT + (size_t)(n0 + nt * 16 + l15) * ldk + k0 + quad * 8);
#pragma unroll
            for (int mi = 0; mi < MW; ++mi)
                acc[mi][nt] = __builtin_amdgcn_mfma_f32_16x16x32_bf16(a[mi], b, acc[mi][nt], 0, 0, 0);
        }
    }

#pragma unroll
    for (int mi = 0; mi < MW; ++mi)
#pragma unroll
        for (int nt = 0; nt < NT; ++nt) {
            int cl = n0 + nt * 16 + l15;
#pragma unroll
            for (int reg = 0; reg < 4; ++reg) {
                int r = m0 + mi * 16 + quad * 4 + reg;
                float v = acc[mi][nt][reg];
                if (EPI == 0) {
                    C[(size_t)r * ldc + cl] = __float2bfloat16(fmaxf(v + bias[cl], 0.f));
                } else if (EPI == 1) {
                    v += bias[cl];
                    if (cl < 64) {
                        Zbuf[(size_t)r * 64 + cl] = sigmoidf_(v);
                    } else if (cl < 128) {
                        int cc = cl - 64;
                        float g = sigmoidf_(v) * Hf[(size_t)r * 64 + cc];
                        A6[(size_t)r * 384 + cc] = __float2bfloat16(g);
                    } else {
                        int cc = cl - 128;
                        hxbuf[(size_t)r * 64 + cc] = v;
                    }
                } else {
                    float pre = v + bias[cl] + hxbuf[(size_t)r * 64 + cl];
                    float ht = tanhf(pre);
                    float z = Zbuf[(size_t)r * 64 + cl];
                    float h = Hf[(size_t)r * 64 + cl];
                    float hn = fmaxf(z * h + (1.f - z) * ht, 0.f);
                    Hf[(size_t)r * 64 + cl] = hn;
                    A6[(size_t)r * 384 + 64 + cl] = __float2bfloat16(hn);
                    if (xsrc)   // stage X_{t+1} into col 0 (streaming, hides dtype branch)
                        A6[(size_t)r * 384 + cl] =
                            __float2bfloat16(loadf(xsrc, xoff + (size_t)r * 64 + cl, isf32));
                }
            }
        }
}

// Hf f32 [BN x 64] flat == Hdense [4096 x 1280] flat; convert to bf16
__global__ void convert_h(const float* __restrict__ Hf, __hip_bfloat16* __restrict__ Hd) {
    int idx = blockIdx.x * 256 + threadIdx.x;
    Hd[idx] = __float2bfloat16(Hf[idx]);
}

// final layer + softmax(2); one wave per batch row
__global__ void mlp3_kernel(const __hip_bfloat16* __restrict__ h2, const float* __restrict__ W3f,
                            const float* __restrict__ b3f, void* __restrict__ out,
                            const int* __restrict__ flagp) {
    int isf32 = *flagp;
    int b = blockIdx.x * 4 + (threadIdx.x >> 6);
    int lane = threadIdx.x & 63;
    float a0 = 0.f, a1 = 0.f;
    for (int k = lane; k < D3; k += 64) {
        float h = bf2f(h2[(size_t)b * D3 + k]);
        a0 = fmaf(h, W3f[k * 2 + 0], a0);
        a1 = fmaf(h, W3f[k * 2 + 1], a1);
    }
    for (int off = 32; off; off >>= 1) {
        a0 += __shfl_down(a0, off, 64);
        a1 += __shfl_down(a1, off, 64);
    }
    if (lane == 0) {
        a0 += b3f[0];
        a1 += b3f[1];
        float m = fmaxf(a0, a1);
        float e0 = expf(a0 - m), e1 = expf(a1 - m);
        float s = e0 + e1;
        if (isf32) {
            ((float*)out)[b * 2 + 0] = e0 / s;
            ((float*)out)[b * 2 + 1] = e1 / s;
        } else {
            ((__hip_bfloat16*)out)[b * 2 + 0] = __float2bfloat16(e0 / s);
            ((__hip_bfloat16*)out)[b * 2 + 1] = __float2bfloat16(e1 / s);
        }
    }
}

// ---------------- host ----------------
extern "C" void kernel_launch(void* const* d_in, const int* in_sizes, int n_in,
                              void* d_out, int out_size, void* d_ws, size_t ws_size,
                              hipStream_t stream) {
    const void* x   = d_in[0];
    const int*  ei  = (const int*)d_in[1];
    const void* ew  = d_in[2];
    const void* Wxz = d_in[3];
    const void* bxz = d_in[4];
    const void* Whz = d_in[5];
    const void* bhz = d_in[6];
    const void* Wxr = d_in[7];
    const void* bxr = d_in[8];
    const void* Whr = d_in[9];
    const void* bhr = d_in[10];
    const void* Wxh = d_in[11];
    const void* bxh = d_in[12];
    const void* Whh = d_in[13];
    const void* bhh = d_in[14];
    const void* W1  = d_in[15];
    const void* b1  = d_in[16];
    const void* W2  = d_in[17];
    const void* b2  = d_in[18];
    const void* W3  = d_in[19];
    const void* b3  = d_in[20];

    char* ws = (char*)d_ws;
    size_t off = 0;
    auto alloc = [&](size_t bytes) { char* p = ws + off; off += (bytes + 255) & ~(size_t)255; return p; };
    __hip_bfloat16* A6  = (__hip_bfloat16*)alloc((size_t)BN * 384 * 2);  // bf16 state
    float* Hf    = (float*)alloc((size_t)BN * 64 * 4);                   // precise H
    float* Zbuf  = (float*)alloc((size_t)BN * 64 * 4);
    float* hxbuf = (float*)alloc((size_t)BN * 64 * 4);
    __hip_bfloat16* Hd  = (__hip_bfloat16*)alloc((size_t)BN * 64 * 2);   // Hdense bf16
    __hip_bfloat16* h1  = (__hip_bfloat16*)alloc((size_t)BATCH * D2 * 2);
    __hip_bfloat16* h2  = (__hip_bfloat16*)alloc((size_t)BATCH * D3 * 2);
    float* deg    = (float*)alloc((size_t)BN * 4);
    int*   counts = (int*)alloc((size_t)BN * 4);
    int*   rowptr = (int*)alloc((size_t)(BN + 1) * 4);
    int*   cursor = (int*)alloc((size_t)BN * 4);
    int2*  cpack  = (int2*)alloc((size_t)E_EDGES * 8);
    __hip_bfloat16* WgT = (__hip_bfloat16*)alloc(192 * 384 * 2);
    __hip_bfloat16* WcT = (__hip_bfloat16*)alloc(64 * 192 * 2);
    float* biasg  = (float*)alloc(192 * 4);
    float* biasc  = (float*)alloc(64 * 4);
    __hip_bfloat16* W1T = (__hip_bfloat16*)alloc((size_t)D2 * D1 * 2);
    float* bias1  = (float*)alloc(D2 * 4);
    __hip_bfloat16* W2T = (__hip_bfloat16*)alloc((size_t)D3 * D2 * 2);
    float* bias2  = (float*)alloc(D3 * 4);
    float* W3f    = (float*)alloc(D3 * 2 * 4);
    float* b3f    = (float*)alloc(2 * 4);
    int*   flag   = (int*)alloc(256);
    (void)ws_size; (void)in_sizes; (void)n_in; (void)out_size;

    hipMemsetAsync(A6, 0, (size_t)BN * 384 * 2, stream);   // H and all chains = 0
    hipMemsetAsync(Hf, 0, (size_t)BN * 64 * 4, stream);    // H0 = 0
    hipMemsetAsync(deg, 0, (size_t)BN * 4, stream);
    hipMemsetAsync(counts, 0, (size_t)BN * 4, stream);

    detect_dtype<<<1, 64, 0, stream>>>(x, flag);

    const int EB = E_EDGES / 256;
    deg_count_kernel<<<EB, 256, 0, stream>>>(ei, ew, deg, counts, flag);
    scan_kernel<<<1, 1024, 0, stream>>>(counts, rowptr, cursor);
    fill_kernel<<<EB, 256, 0, stream>>>(ei, ew, deg, cursor, cpack, flag);
    prep_weights<<<4344, 256, 0, stream>>>(Wxz, Whz, Wxr, Whr, Wxh, Whh,
                                           bxz, bhz, bxr, bhr, bxh, bhh,
                                           W1, b1, W2, b2, W3, b3,
                                           WgT, WcT, biasg, biasc,
                                           W1T, bias1, W2T, bias2, W3f, b3f, flag);
    init_x_kernel<<<(BN * 64) / 256, 256, 0, stream>>>(x, flag, A6);

    const int RB = BN / 4;  // 20480 blocks, wave-per-row
    for (int t = 0; t < T_STEPS; ++t) {
        // X1|H1 = L [Xt|H]   (one 256B gather/edge)
        phase_pair_kernel<<<RB, 256, 0, stream>>>(rowptr, cpack, A6, 0, 256);
        // X2|H2 = L [X1|H1]
        phase_pair_kernel<<<RB, 256, 0, stream>>>(rowptr, cpack, A6, 256, 512);
        // gates: [BN x 384] @ WgT^T -> 192 cols (Z | R->G | hx)
        mfma_gemm<2, 12, 1, 64><<<dim3(BN / 128, 1), 256, 0, stream>>>(
            A6, 384, WgT, 384, biasg, 384, Zbuf, hxbuf, Hf, A6, nullptr, 0,
            nullptr, 0ull, nullptr);
        spmm_b_kernel<<<RB, 256, 0, stream>>>(rowptr, cpack, A6, 0, 128);    // G1 = L G
        spmm_b_kernel<<<RB, 256, 0, stream>>>(rowptr, cpack, A6, 128, 256);  // G2 = L G1
        // candidate: k-blocks {G:0, G1:128, G2:256} @ WcT^T -> 64 cols, fused GRU update
        const void* xn = (t + 1 < T_STEPS) ? x : nullptr;
        unsigned long long xo = (unsigned long long)(t + 1) * BN * 64;
        mfma_gemm<2, 4, 2, 128><<<dim3(BN / 128, 1), 256, 0, stream>>>(
            A6, 384, WcT, 192, biasc, 192, Zbuf, hxbuf, Hf, A6, nullptr, 0,
            xn, xo, flag);
    }

    convert_h<<<(BN * 64) / 256, 256, 0, stream>>>(Hf, Hd);
    // h1 = relu(Hd @ W1 + b1): M=4096, N=640, K=1280
    mfma_gemm<1, 4, 0, 64><<<dim3(BATCH / 64, D2 / 64), 256, 0, stream>>>(
        Hd, D1, W1T, D1, bias1, D1, nullptr, nullptr, nullptr, nullptr, h1, D2,
        nullptr, 0ull, nullptr);
    // h2 = relu(h1 @ W2 + b2): M=4096, N=320, K=640
    mfma_gemm<1, 4, 0, 64><<<dim3(BATCH / 64, D3 / 64), 256, 0, stream>>>(
        h1, D2, W2T, D2, bias2, D2, nullptr, nullptr, nullptr, nullptr, h2, D3,
        nullptr, 0ull, nullptr);
    mlp3_kernel<<<BATCH / 4, 256, 0, stream>>>(h2, W3f, b3f, d_out, flag);
}

// Round 3
// 4041.669 us; speedup vs baseline: 1.4580x; 1.2833x over previous
//
#include <hip/hip_runtime.h>
#include <hip/hip_bf16.h>
#include <math.h>

#define T_STEPS 16
#define N_NODES 20
#define BATCH 4096
#define F_DIM 64
#define BN 81920
#define E_EDGES 327680
#define D1 1280
#define D2 640
#define D3 320

typedef __attribute__((ext_vector_type(8))) short short8;
typedef __attribute__((ext_vector_type(4))) float floatx4;

static __device__ __forceinline__ float bf2f(__hip_bfloat16 v) { return __bfloat162float(v); }
static __device__ __forceinline__ float sigmoidf_(float x) { return 1.f / (1.f + expf(-x)); }
static __device__ __forceinline__ float loadf(const void* p, size_t i, int isf32) {
    return isf32 ? ((const float*)p)[i] : bf2f(((const __hip_bfloat16*)p)[i]);
}
static __device__ __forceinline__ float bflo(unsigned int u) { return __uint_as_float(u << 16); }
static __device__ __forceinline__ float bfhi(unsigned int u) { return __uint_as_float(u & 0xffff0000u); }
static __device__ __forceinline__ unsigned int f2bf_bits(float f) {
    __hip_bfloat16 b = __float2bfloat16(f);
    unsigned short us;
    __builtin_memcpy(&us, &b, 2);
    return (unsigned int)us;
}

// A6 element-column layout (row stride 384 bf16 = 768 B):
//   [0:Xt | 64:H | 128:X1 | 192:H1 | 256:X2 | 320:H2]
// Gbuf element-column layout (row stride 192 bf16 = 384 B): [G | G1 | G2]
// gates epilogue:  G -> Gbuf col 0   (A6 untouched -> N-split is race-free)
// spmm1: G1 = L G -> Gbuf col 64;  spmm2: G2 = L G1 -> Gbuf col 128
// cand epilogue: Hn -> A6 col 64 (+Hf), X_{t+1} -> A6 col 0
//                (last step: Hn bf16 -> Hd only)

// ---------------- dtype detection (bf16 vs f32 inputs) ----------------
__global__ void detect_dtype(const void* __restrict__ x, int* __restrict__ flag) {
    int lane = threadIdx.x;
    const unsigned short* u = (const unsigned short*)x;
    int bad = 0;
    for (int i = lane; i < 256; i += 64) {
        int e = (u[i] >> 7) & 0xFF;
        if (e >= 141) bad = 1;
    }
    unsigned long long m = __ballot(bad != 0);
    if (lane == 0) flag[0] = (m != 0ull) ? 1 : 0;
}

// ---------------- CSR build ----------------
__global__ void deg_count_kernel(const int* __restrict__ ei, const void* __restrict__ ew,
                                 float* __restrict__ deg, int* __restrict__ counts,
                                 const int* __restrict__ flagp) {
    int isf32 = *flagp;
    int e = blockIdx.x * 256 + threadIdx.x;
    if (e < E_EDGES) {
        atomicAdd(&deg[ei[e]], loadf(ew, e, isf32));
        atomicAdd(&counts[ei[E_EDGES + e]], 1);
    }
}

__global__ void scan_kernel(const int* __restrict__ counts, int* __restrict__ rowptr,
                            int* __restrict__ cursor) {
    __shared__ int s[1024];
    int t = threadIdx.x;
    int base = t * 80;
    int sum = 0;
    for (int i = 0; i < 80; ++i) sum += counts[base + i];
    s[t] = sum;
    __syncthreads();
    for (int off = 1; off < 1024; off <<= 1) {
        int v = (t >= off) ? s[t - off] : 0;
        __syncthreads();
        s[t] += v;
        __syncthreads();
    }
    int run = (t > 0) ? s[t - 1] : 0;
    for (int i = 0; i < 80; ++i) {
        rowptr[base + i] = run;
        cursor[base + i] = run;
        run += counts[base + i];
    }
    if (t == 1023) rowptr[BN] = run;
}

__global__ void fill_kernel(const int* __restrict__ ei, const void* __restrict__ ew,
                            const float* __restrict__ deg,
                            int* __restrict__ cursor, int2* __restrict__ cpack,
                            const int* __restrict__ flagp) {
    int isf32 = *flagp;
    int e = blockIdx.x * 256 + threadIdx.x;
    if (e < E_EDGES) {
        int s = ei[e], d = ei[E_EDGES + e];
        float w = loadf(ew, e, isf32);
        float ds = deg[s], dd = deg[d];
        float is = (ds > 0.f) ? (1.f / sqrtf(ds)) : 0.f;
        float id = (dd > 0.f) ? (1.f / sqrtf(dd)) : 0.f;
        int p = atomicAdd(&cursor[d], 1);
        cpack[p] = make_int2(s, __float_as_int(-is * w * id));
    }
}

// ---------------- weight prep ----------------
// WgT[192][384]: n = grp*64+cc (z|r|hx), k-order matches A6 cols:
//   m in {X-T0, H-T0, X-T1, H-T1, X-T2, H-T2}  (m even = X-chain, odd = H-chain)
// Cheb fold onto stored [V, L V, L^2 V]: c0 = W0 - W2, c1 = W1, c2 = 2 W2.
// WcT[64][192] from Whh (k-order [G,G1,G2], same fold); W1T/W2T transposed MLP.
__global__ void prep_weights(const void* Wxz, const void* Whz,
                             const void* Wxr, const void* Whr,
                             const void* Wxh, const void* Whh,
                             const void* bxz, const void* bhz,
                             const void* bxr, const void* bhr,
                             const void* bxh, const void* bhh,
                             const void* W1, const void* b1,
                             const void* W2, const void* b2,
                             const void* W3, const void* b3,
                             __hip_bfloat16* WgT, __hip_bfloat16* WcT,
                             float* biasg, float* biasc,
                             __hip_bfloat16* W1T, float* bias1,
                             __hip_bfloat16* W2T, float* bias2,
                             float* W3f, float* b3f, const int* __restrict__ flagp) {
    int isf32 = *flagp;
    int tid = blockIdx.x * 256 + threadIdx.x;
    if (tid < 73728) {
        int n = tid / 384, kk = tid - (tid / 384) * 384;
        int m = kk >> 6, jj = kk & 63;
        int grp = n >> 6, cc = n & 63;
        const void* Wx = (grp == 0) ? Wxz : ((grp == 1) ? Wxr : Wxh);
        const void* Wh = (grp == 0) ? Whz : ((grp == 1) ? Whr : nullptr);
        int ch = m & 1;          // 0 = X-chain, 1 = H-chain
        int ti = m >> 1;         // Chebyshev index 0..2
        const void* W = ch ? Wh : Wx;
        float v = 0.f;
        int o = jj * 64 + cc;
        if (W) {
            if (ti == 0)      v = loadf(W, o, isf32) - loadf(W, 2 * 4096 + o, isf32);
            else if (ti == 1) v = loadf(W, 4096 + o, isf32);
            else              v = 2.f * loadf(W, 2 * 4096 + o, isf32);
        }
        WgT[tid] = __float2bfloat16(v);
    } else if (tid < 86016) {
        int t2 = tid - 73728;
        int n = t2 / 192, kk = t2 - (t2 / 192) * 192;
        int m = kk >> 6, jj = kk & 63;
        int o = jj * 64 + n;
        float v;
        if (m == 0)      v = loadf(Whh, o, isf32) - loadf(Whh, 2 * 4096 + o, isf32);
        else if (m == 1) v = loadf(Whh, 4096 + o, isf32);
        else             v = 2.f * loadf(Whh, 2 * 4096 + o, isf32);
        WcT[t2] = __float2bfloat16(v);
    } else if (tid < 86208) {
        int c = tid - 86016;
        int grp = c >> 6, cc = c & 63;
        float v = (grp == 0) ? (loadf(bxz, cc, isf32) + loadf(bhz, cc, isf32))
                 : (grp == 1) ? (loadf(bxr, cc, isf32) + loadf(bhr, cc, isf32))
                              : loadf(bxh, cc, isf32);
        biasg[c] = v;
    } else if (tid < 86272) {
        biasc[tid - 86208] = loadf(bhh, tid - 86208, isf32);
    } else if (tid < 86912) {
        bias1[tid - 86272] = loadf(b1, tid - 86272, isf32);
    } else if (tid < 87232) {
        bias2[tid - 86912] = loadf(b2, tid - 86912, isf32);
    } else if (tid < 87872) {
        W3f[tid - 87232] = loadf(W3, tid - 87232, isf32);
    } else if (tid < 87874) {
        b3f[tid - 87872] = loadf(b3, tid - 87872, isf32);
    } else if (tid < 907074) {
        int t = tid - 87874;                       // W1T[n][k] = W1[k][n]
        int n = t / 1280, k = t - (t / 1280) * 1280;
        W1T[t] = __float2bfloat16(loadf(W1, (size_t)k * 640 + n, isf32));
    } else if (tid < 1111874) {
        int t = tid - 907074;                      // W2T[n][k] = W2[k][n]
        int n = t / 640, k = t - (t / 640) * 640;
        W2T[t] = __float2bfloat16(loadf(W2, (size_t)k * 320 + n, isf32));
    }
}

// ---------------- X_0 staging: A6 col 0 <- x[0] ----------------
__global__ void init_x_kernel(const void* __restrict__ x, const int* __restrict__ flagp,
                              __hip_bfloat16* __restrict__ A6) {
    int isf32 = *flagp;
    int idx = blockIdx.x * 256 + threadIdx.x;
    int r = idx >> 6, c = idx & 63;
    A6[(size_t)r * 384 + c] = __float2bfloat16(loadf(x, idx, isf32));
}

// ---------------- paired-chain SpMV on A6: one 256B gather serves both chains ----------------
__global__ void phase_pair_kernel(const int* __restrict__ rowptr, const int2* __restrict__ cpack,
                                  __hip_bfloat16* __restrict__ A6, int in_boff, int out_boff) {
    int row = __builtin_amdgcn_readfirstlane(blockIdx.x * 4 + (threadIdx.x >> 6));
    int lane = threadIdx.x & 63;
    int e0 = rowptr[row], e1 = rowptr[row + 1];
    const char* base = (const char*)A6 + in_boff;
    int boff = lane * 4;
    float ax = 0.f, ay = 0.f, bx = 0.f, by = 0.f;
    int e = e0;
    for (; e + 2 <= e1; e += 2) {
        int2 c0 = cpack[e], c1 = cpack[e + 1];
        unsigned int u0 = *(const unsigned int*)(base + (size_t)c0.x * 768 + boff);
        unsigned int u1 = *(const unsigned int*)(base + (size_t)c1.x * 768 + boff);
        float v0 = __int_as_float(c0.y), v1 = __int_as_float(c1.y);
        ax = fmaf(v0, bflo(u0), ax); ay = fmaf(v0, bfhi(u0), ay);
        bx = fmaf(v1, bflo(u1), bx); by = fmaf(v1, bfhi(u1), by);
    }
    if (e < e1) {
        int2 c0 = cpack[e];
        unsigned int u0 = *(const unsigned int*)(base + (size_t)c0.x * 768 + boff);
        float v0 = __int_as_float(c0.y);
        ax = fmaf(v0, bflo(u0), ax); ay = fmaf(v0, bfhi(u0), ay);
    }
    ax += bx; ay += by;
    unsigned int pk = f2bf_bits(ax) | (f2bf_bits(ay) << 16);
    *(unsigned int*)((char*)A6 + (size_t)row * 768 + out_boff +
                     ((lane >> 5) << 7) + ((lane & 31) << 2)) = pk;
}

// ---------------- row-paired single-chain SpMV on Gbuf (row stride 384 B) ----------------
// Two rows per wave: lanes 0-31 -> row 2i, lanes 32-63 -> row 2i+1.
// Each lane covers an element pair (bf16x2 dword). Offsets in BYTES.
__global__ void spmm_pair_kernel(const int* __restrict__ rowptr, const int2* __restrict__ cpack,
                                 __hip_bfloat16* __restrict__ Gbuf, int in_boff, int out_boff) {
    int lane = threadIdx.x & 63;
    int half = lane >> 5, lh = lane & 31;
    int row = (blockIdx.x * 4 + (threadIdx.x >> 6)) * 2 + half;
    int e0 = rowptr[row], e1 = rowptr[row + 1];
    const char* base = (const char*)Gbuf + in_boff;
    int boff = lh * 4;
    float ax = 0.f, ay = 0.f, bx = 0.f, by = 0.f;
    int e = e0;
    for (; e + 2 <= e1; e += 2) {
        int2 c0 = cpack[e], c1 = cpack[e + 1];
        unsigned int u0 = *(const unsigned int*)(base + (size_t)c0.x * 384 + boff);
        unsigned int u1 = *(const unsigned int*)(base + (size_t)c1.x * 384 + boff);
        float v0 = __int_as_float(c0.y), v1 = __int_as_float(c1.y);
        ax = fmaf(v0, bflo(u0), ax); ay = fmaf(v0, bfhi(u0), ay);
        bx = fmaf(v1, bflo(u1), bx); by = fmaf(v1, bfhi(u1), by);
    }
    if (e < e1) {
        int2 c0 = cpack[e];
        unsigned int u0 = *(const unsigned int*)(base + (size_t)c0.x * 384 + boff);
        float v0 = __int_as_float(c0.y);
        ax = fmaf(v0, bflo(u0), ax); ay = fmaf(v0, bfhi(u0), ay);
    }
    ax += bx; ay += by;
    unsigned int pk = f2bf_bits(ax) | (f2bf_bits(ay) << 16);
    *(unsigned int*)((char*)Gbuf + (size_t)row * 384 + out_boff + boff) = pk;
}

// ---------------- MFMA GEMM (fragment-direct, no LDS) ----------------
// C[M x N] = epi(A[M x K]_bf16 @ WT[N x K]_bf16^T + bias)
// EPI: 0 = relu -> C(bf16); 1 = gates (Z f32, G=sig(R)*Hf -> Gbuf col 0, hx f32);
//      2 = cand+GRU (xsrc != null: Hn -> Hf + A6 col64, X_{t+1} -> A6 col 0;
//                    xsrc == null (last step): Hn bf16 -> Hdout only)
// Epilogue writes never alias any GEMM input -> N-split (grid.y) is race-free.
template <int MW, int NT, int EPI>
__launch_bounds__(256)
__global__ void mfma_gemm(const __hip_bfloat16* __restrict__ A, int lda,
                          const __hip_bfloat16* __restrict__ WT, int ldk,
                          const float* __restrict__ bias, int K,
                          float* __restrict__ Zbuf, float* __restrict__ hxbuf,
                          float* __restrict__ Hf, __hip_bfloat16* A6,
                          __hip_bfloat16* __restrict__ Gbuf,
                          __hip_bfloat16* __restrict__ C, int ldc,
                          const void* __restrict__ xsrc, unsigned long long xoff,
                          const int* __restrict__ flagp,
                          __hip_bfloat16* __restrict__ Hdout) {
    int wave = threadIdx.x >> 6;
    int lane = threadIdx.x & 63;
    int l15 = lane & 15, quad = lane >> 4;
    int m0 = blockIdx.x * (MW * 64) + wave * (MW * 16);
    int n0 = blockIdx.y * (NT * 16);
    int isf32 = 0;
    if (EPI == 2 && flagp) isf32 = *flagp;

    floatx4 acc[MW][NT];
#pragma unroll
    for (int mi = 0; mi < MW; ++mi)
#pragma unroll
        for (int nt = 0; nt < NT; ++nt) acc[mi][nt] = (floatx4){0.f, 0.f, 0.f, 0.f};

    for (int k0 = 0; k0 < K; k0 += 32) {
        short8 a[MW];
#pragma unroll
        for (int mi = 0; mi < MW; ++mi)
            a[mi] = *(const short8*)(A + (size_t)(m0 + mi * 16 + l15) * lda + k0 + quad * 8);
#pragma unroll
        for (int nt = 0; nt < NT; ++nt) {
            short8 b = *(const short8*)(WT + (size_t)(n0 + nt * 16 + l15) * ldk + k0 + quad * 8);
#pragma unroll
            for (int mi = 0; mi < MW; ++mi)
                acc[mi][nt] = __builtin_amdgcn_mfma_f32_16x16x32_bf16(a[mi], b, acc[mi][nt], 0, 0, 0);
        }
    }

#pragma unroll
    for (int mi = 0; mi < MW; ++mi)
#pragma unroll
        for (int nt = 0; nt < NT; ++nt) {
            int cl = n0 + nt * 16 + l15;
#pragma unroll
            for (int reg = 0; reg < 4; ++reg) {
                int r = m0 + mi * 16 + quad * 4 + reg;
                float v = acc[mi][nt][reg];
                if (EPI == 0) {
                    C[(size_t)r * ldc + cl] = __float2bfloat16(fmaxf(v + bias[cl], 0.f));
                } else if (EPI == 1) {
                    v += bias[cl];
                    if (cl < 64) {
                        Zbuf[(size_t)r * 64 + cl] = sigmoidf_(v);
                    } else if (cl < 128) {
                        int cc = cl - 64;
                        float g = sigmoidf_(v) * Hf[(size_t)r * 64 + cc];
                        Gbuf[(size_t)r * 192 + cc] = __float2bfloat16(g);
                    } else {
                        int cc = cl - 128;
                        hxbuf[(size_t)r * 64 + cc] = v;
                    }
                } else {
                    float pre = v + bias[cl] + hxbuf[(size_t)r * 64 + cl];
                    float ht = tanhf(pre);
                    float z = Zbuf[(size_t)r * 64 + cl];
                    float h = Hf[(size_t)r * 64 + cl];
                    float hn = fmaxf(z * h + (1.f - z) * ht, 0.f);
                    __hip_bfloat16 hb = __float2bfloat16(hn);
                    if (xsrc) {
                        Hf[(size_t)r * 64 + cl] = hn;
                        A6[(size_t)r * 384 + 64 + cl] = hb;
                        // stage X_{t+1} into col 0 (streaming, hides dtype branch)
                        A6[(size_t)r * 384 + cl] =
                            __float2bfloat16(loadf(xsrc, xoff + (size_t)r * 64 + cl, isf32));
                    } else {
                        Hdout[(size_t)r * 64 + cl] = hb;   // last step: Hdense bf16
                    }
                }
            }
        }
}

// final layer + softmax(2); one wave per batch row
__global__ void mlp3_kernel(const __hip_bfloat16* __restrict__ h2, const float* __restrict__ W3f,
                            const float* __restrict__ b3f, void* __restrict__ out,
                            const int* __restrict__ flagp) {
    int isf32 = *flagp;
    int b = blockIdx.x * 4 + (threadIdx.x >> 6);
    int lane = threadIdx.x & 63;
    float a0 = 0.f, a1 = 0.f;
    for (int k = lane; k < D3; k += 64) {
        float h = bf2f(h2[(size_t)b * D3 + k]);
        a0 = fmaf(h, W3f[k * 2 + 0], a0);
        a1 = fmaf(h, W3f[k * 2 + 1], a1);
    }
    for (int off = 32; off; off >>= 1) {
        a0 += __shfl_down(a0, off, 64);
        a1 += __shfl_down(a1, off, 64);
    }
    if (lane == 0) {
        a0 += b3f[0];
        a1 += b3f[1];
        float m = fmaxf(a0, a1);
        float e0 = expf(a0 - m), e1 = expf(a1 - m);
        float s = e0 + e1;
        if (isf32) {
            ((float*)out)[b * 2 + 0] = e0 / s;
            ((float*)out)[b * 2 + 1] = e1 / s;
        } else {
            ((__hip_bfloat16*)out)[b * 2 + 0] = __float2bfloat16(e0 / s);
            ((__hip_bfloat16*)out)[b * 2 + 1] = __float2bfloat16(e1 / s);
        }
    }
}

// ---------------- host ----------------
extern "C" void kernel_launch(void* const* d_in, const int* in_sizes, int n_in,
                              void* d_out, int out_size, void* d_ws, size_t ws_size,
                              hipStream_t stream) {
    const void* x   = d_in[0];
    const int*  ei  = (const int*)d_in[1];
    const void* ew  = d_in[2];
    const void* Wxz = d_in[3];
    const void* bxz = d_in[4];
    const void* Whz = d_in[5];
    const void* bhz = d_in[6];
    const void* Wxr = d_in[7];
    const void* bxr = d_in[8];
    const void* Whr = d_in[9];
    const void* bhr = d_in[10];
    const void* Wxh = d_in[11];
    const void* bxh = d_in[12];
    const void* Whh = d_in[13];
    const void* bhh = d_in[14];
    const void* W1  = d_in[15];
    const void* b1  = d_in[16];
    const void* W2  = d_in[17];
    const void* b2  = d_in[18];
    const void* W3  = d_in[19];
    const void* b3  = d_in[20];

    char* ws = (char*)d_ws;
    size_t off = 0;
    auto alloc = [&](size_t bytes) { char* p = ws + off; off += (bytes + 255) & ~(size_t)255; return p; };
    __hip_bfloat16* A6  = (__hip_bfloat16*)alloc((size_t)BN * 384 * 2);  // bf16 state
    __hip_bfloat16* Gbuf = (__hip_bfloat16*)alloc((size_t)BN * 192 * 2); // [G|G1|G2]
    float* Hf    = (float*)alloc((size_t)BN * 64 * 4);                   // precise H
    float* Zbuf  = (float*)alloc((size_t)BN * 64 * 4);
    float* hxbuf = (float*)alloc((size_t)BN * 64 * 4);
    __hip_bfloat16* Hd  = (__hip_bfloat16*)alloc((size_t)BN * 64 * 2);   // Hdense bf16
    __hip_bfloat16* h1  = (__hip_bfloat16*)alloc((size_t)BATCH * D2 * 2);
    __hip_bfloat16* h2  = (__hip_bfloat16*)alloc((size_t)BATCH * D3 * 2);
    float* deg    = (float*)alloc((size_t)BN * 4);
    int*   counts = (int*)alloc((size_t)BN * 4);
    int*   rowptr = (int*)alloc((size_t)(BN + 1) * 4);
    int*   cursor = (int*)alloc((size_t)BN * 4);
    int2*  cpack  = (int2*)alloc((size_t)E_EDGES * 8);
    __hip_bfloat16* WgT = (__hip_bfloat16*)alloc(192 * 384 * 2);
    __hip_bfloat16* WcT = (__hip_bfloat16*)alloc(64 * 192 * 2);
    float* biasg  = (float*)alloc(192 * 4);
    float* biasc  = (float*)alloc(64 * 4);
    __hip_bfloat16* W1T = (__hip_bfloat16*)alloc((size_t)D2 * D1 * 2);
    float* bias1  = (float*)alloc(D2 * 4);
    __hip_bfloat16* W2T = (__hip_bfloat16*)alloc((size_t)D3 * D2 * 2);
    float* bias2  = (float*)alloc(D3 * 4);
    float* W3f    = (float*)alloc(D3 * 2 * 4);
    float* b3f    = (float*)alloc(2 * 4);
    int*   flag   = (int*)alloc(256);
    (void)ws_size; (void)in_sizes; (void)n_in; (void)out_size;

    hipMemsetAsync(A6, 0, (size_t)BN * 384 * 2, stream);   // H and all chains = 0
    hipMemsetAsync(Hf, 0, (size_t)BN * 64 * 4, stream);    // H0 = 0
    hipMemsetAsync(deg, 0, (size_t)BN * 4, stream);
    hipMemsetAsync(counts, 0, (size_t)BN * 4, stream);

    detect_dtype<<<1, 64, 0, stream>>>(x, flag);

    const int EB = E_EDGES / 256;
    deg_count_kernel<<<EB, 256, 0, stream>>>(ei, ew, deg, counts, flag);
    scan_kernel<<<1, 1024, 0, stream>>>(counts, rowptr, cursor);
    fill_kernel<<<EB, 256, 0, stream>>>(ei, ew, deg, cursor, cpack, flag);
    prep_weights<<<4344, 256, 0, stream>>>(Wxz, Whz, Wxr, Whr, Wxh, Whh,
                                           bxz, bhz, bxr, bhr, bxh, bhh,
                                           W1, b1, W2, b2, W3, b3,
                                           WgT, WcT, biasg, biasc,
                                           W1T, bias1, W2T, bias2, W3f, b3f, flag);
    init_x_kernel<<<(BN * 64) / 256, 256, 0, stream>>>(x, flag, A6);

    const int RB = BN / 4;    // wave-per-row kernels
    const int RB2 = BN / 8;   // two-rows-per-wave kernels
    for (int t = 0; t < T_STEPS; ++t) {
        // X1|H1 = L [Xt|H]   (one 256B gather/edge)
        phase_pair_kernel<<<RB, 256, 0, stream>>>(rowptr, cpack, A6, 0, 256);
        // X2|H2 = L [X1|H1]
        phase_pair_kernel<<<RB, 256, 0, stream>>>(rowptr, cpack, A6, 256, 512);
        // gates: [BN x 384] @ WgT^T -> 192 cols (Z | R->G(Gbuf) | hx); N-split grid.y=2
        mfma_gemm<2, 6, 1><<<dim3(BN / 128, 2), 256, 0, stream>>>(
            A6, 384, WgT, 384, biasg, 384, Zbuf, hxbuf, Hf, A6, Gbuf, nullptr, 0,
            nullptr, 0ull, nullptr, nullptr);
        // G-chain inside Gbuf (byte offsets: G=0, G1=256, G2=512... stride 384B)
        spmm_pair_kernel<<<RB2, 256, 0, stream>>>(rowptr, cpack, Gbuf, 0, 128);    // G1 = L G
        spmm_pair_kernel<<<RB2, 256, 0, stream>>>(rowptr, cpack, Gbuf, 128, 256);  // G2 = L G1
        // candidate: Gbuf[BN x 192] @ WcT^T -> 64 cols, fused GRU update; N-split grid.y=2
        const void* xn = (t + 1 < T_STEPS) ? x : nullptr;
        unsigned long long xo = (unsigned long long)(t + 1) * BN * 64;
        mfma_gemm<2, 2, 2><<<dim3(BN / 128, 2), 256, 0, stream>>>(
            Gbuf, 192, WcT, 192, biasc, 192, Zbuf, hxbuf, Hf, A6, Gbuf, nullptr, 0,
            xn, xo, flag, Hd);
    }

    // h1 = relu(Hd @ W1 + b1): M=4096, N=640, K=1280
    mfma_gemm<1, 4, 0><<<dim3(BATCH / 64, D2 / 64), 256, 0, stream>>>(
        Hd, D1, W1T, D1, bias1, D1, nullptr, nullptr, nullptr, nullptr, nullptr, h1, D2,
        nullptr, 0ull, nullptr, nullptr);
    // h2 = relu(h1 @ W2 + b2): M=4096, N=320, K=640
    mfma_gemm<1, 4, 0><<<dim3(BATCH / 64, D3 / 64), 256, 0, stream>>>(
        h1, D2, W2T, D2, bias2, D2, nullptr, nullptr, nullptr, nullptr, nullptr, h2, D3,
        nullptr, 0ull, nullptr, nullptr);
    mlp3_kernel<<<BATCH / 4, 256, 0, stream>>>(h2, W3f, b3f, d_out, flag);
}